// Round 16
// baseline (1175.724 us; speedup 1.0000x reference)
//
#include <hip/hip_runtime.h>
#include <math.h>

typedef _Float16 f16;
typedef __attribute__((ext_vector_type(4))) _Float16 f16x4;
typedef __attribute__((ext_vector_type(8))) _Float16 f16x8;
typedef __attribute__((ext_vector_type(4))) float f32x4;
typedef __attribute__((ext_vector_type(4))) unsigned int u32x4;

// exact-GELU via Abramowitz-Stegun 7.1.26 erf (|err| <= 1.5e-7)
__device__ __forceinline__ float gelu_f(float x) {
    float xs = x * 0.70710678118654752440f;
    float ax = fabsf(xs);
    float t = __builtin_amdgcn_rcpf(1.0f + 0.3275911f * ax);
    float p = t * (0.254829592f + t * (-0.284496736f + t * (1.421413741f +
              t * (-1.453152027f + t * 1.061405429f))));
    float erfv = 1.0f - p * __expf(-ax * ax);
    erfv = copysignf(erfv, xs);
    return 0.5f * x * (1.0f + erfv);
}

__device__ __forceinline__ void nsamp(float cy, float cx, int hi, int wi,
                                      int& iy, int& ix, bool& valid) {
    float fy = rintf(((cy + 1.0f) * (float)hi - 1.0f) * 0.5f);
    float fx = rintf(((cx + 1.0f) * (float)wi - 1.0f) * 0.5f);
    valid = (fy >= 0.0f) && (fy < (float)hi) && (fx >= 0.0f) && (fx < (float)wi);
    iy = (int)fminf(fmaxf(fy, 0.0f), (float)(hi - 1));
    ix = (int)fminf(fmaxf(fx, 0.0f), (float)(wi - 1));
}

// ---- ALL conv weight packs in one launch: OIHW fp32 -> [cout][chunk][tap][ci32] f16 ----
__global__ __launch_bounds__(256) void pack_w_all(
    const float* __restrict__ s0, const float* __restrict__ s1,
    const float* __restrict__ s2, const float* __restrict__ s3,
    const float* __restrict__ s4, const float* __restrict__ s5,
    f16* __restrict__ dst) {
    int i = blockIdx.x * 256 + threadIdx.x;
    const float* src; int Cin, NCH, base;
    if (i < 73728)        { src = s0; Cin = 34;  NCH = 2; base = 0; }
    else if (i < 1253376) { src = s1; Cin = 128; NCH = 4; base = 73728; }
    else if (i < 1400832) { src = s2; Cin = 128; NCH = 4; base = 1253376; }
    else if (i < 1437696) { src = s3; Cin = 31;  NCH = 1; base = 1400832; }
    else if (i < 2617344) { src = s4; Cin = 128; NCH = 4; base = 1437696; }
    else if (i < 2764800) { src = s5; Cin = 128; NCH = 4; base = 2617344; }
    else return;
    int j = i - base;
    int ci = j & 31;
    int tap = (j >> 5) % 9;
    int q = j / 288;
    int chunk = q % NCH;
    int q2 = q / NCH;
    int cout = q2 & 127;
    int conv = q2 >> 7;
    int cin = chunk * 32 + ci;
    float v = (cin < Cin) ? src[((size_t)(conv * 128 + cout) * Cin + cin) * 9 + tap] : 0.f;
    dst[i] = (f16)v;
}

// ---- ALL level MLP packs in one launch: fp32 [K][N] -> f16 [N][NC][32] ----
__global__ __launch_bounds__(256) void pack_lvl_all(
    const float* __restrict__ p0, const float* __restrict__ p1,
    const float* __restrict__ p2, const float* __restrict__ p3,
    const float* __restrict__ p4, const float* __restrict__ p5,
    const float* __restrict__ p6, const float* __restrict__ p7,
    const float* __restrict__ p8, const float* __restrict__ p9,
    f16* __restrict__ dst) {
    int i = blockIdx.x * 256 + threadIdx.x;
    const float* src; int Ksrc, N, NC, base;
    if (i < 106496)      { src = p0; Ksrc = 386; N = 256; NC = 13; base = 0; }
    else if (i < 114688) { src = p1; Ksrc = 128; N = 64;  NC = 4;  base = 106496; }
    else if (i < 122880) { src = p2; Ksrc = 64;  N = 128; NC = 2;  base = 114688; }
    else if (i < 131072) { src = p3; Ksrc = 128; N = 64;  NC = 4;  base = 122880; }
    else if (i < 139264) { src = p4; Ksrc = 64;  N = 128; NC = 2;  base = 131072; }
    else if (i < 245760) { src = p5; Ksrc = 386; N = 256; NC = 13; base = 139264; }
    else if (i < 253952) { src = p6; Ksrc = 128; N = 64;  NC = 4;  base = 245760; }
    else if (i < 262144) { src = p7; Ksrc = 64;  N = 128; NC = 2;  base = 253952; }
    else if (i < 270336) { src = p8; Ksrc = 128; N = 64;  NC = 4;  base = 262144; }
    else if (i < 272320) { src = p9; Ksrc = 64;  N = 31;  NC = 2;  base = 270336; }
    else return;
    int j = i - base;
    int kk = j & 31;
    int c = (j >> 5) % NC;
    int n = j / (32 * NC);
    int k = c * 32 + kk;
    dst[i] = (f16)((k < Ksrc) ? src[(size_t)k * N + n] : 0.f);
}

// concat(HR_MSI, lms) -> padded NHWC fp16 [16][66][66][64]
__global__ __launch_bounds__(256) void build_cc(
    const float* __restrict__ msi, const float* __restrict__ lms,
    f16* __restrict__ out, int total) {
    int i = blockIdx.x * 256 + threadIdx.x;
    if (i >= total) return;
    int ch = i % 34;
    int p = i / 34;
    int x = p & 63, y = (p >> 6) & 63, b = p >> 12;
    float v = (ch < 3) ? msi[(((size_t)(b * 3 + ch) << 6) + y << 6) + x]
                       : lms[(((size_t)(b * 31 + ch - 3) << 6) + y << 6) + x];
    out[((size_t)(b * 66 + y + 1) * 66 + x + 1) * 64 + ch] = v;
}

// LR_HSI -> padded NHWC fp16 [16][18][18][32]
__global__ __launch_bounds__(256) void build_spe(
    const float* __restrict__ in, f16* __restrict__ out, int total) {
    int i = blockIdx.x * 256 + threadIdx.x;
    if (i >= total) return;
    int ch = i % 31;
    int p = i / 31;
    int x = p & 15, y = (p >> 4) & 15, b = p >> 8;
    out[((size_t)(b * 18 + y + 1) * 18 + x + 1) * 32 + ch] =
        (f16)in[(((size_t)(b * 31 + ch) << 4) + y << 4) + x];
}

// ---- implicit-GEMM conv3x3 body: whole tile staged once, 1 barrier ----
template<int PXW, int XSH, int ROWS, int WAVES, int NCHUNK>
__device__ __forceinline__ void conv_body(
    int bx, char* ldsb,
    const f16* __restrict__ in_h,
    const f16* __restrict__ wp, const float* __restrict__ bias,
    const f16* __restrict__ skip_h, f16* __restrict__ out_h,
    f16* __restrict__ out2, int mode) {
    constexpr int XW = 1 << XSH;
    constexpr int PH = XW + 2;
    constexpr int NPX = (ROWS + 2) * PXW;
    constexpr int UPP = NCHUNK * 4;
    constexpr int UNITS = NPX * UPP;
    constexpr int NTH = WAVES * 64;
    constexpr int ITER = (UNITS + NTH - 1) / NTH;
    constexpr int WN = WAVES / 2;
    constexpr int NT = 8 / WN;
    constexpr int MT = (ROWS << XSH) >> 5;
    constexpr int PXB = NCHUNK * 64;

    int tid = threadIdx.x;
    constexpr int NYB = XW / ROWS;
    int b = bx / NYB;
    int y0 = (bx % NYB) * ROWS;
    int wave = tid >> 6, lane = tid & 63;
    int wm = wave / WN, wn = wave % WN;
    int l15 = lane & 15, lk = lane >> 4;

#pragma unroll
    for (int i = 0; i < ITER; ++i) {
        int u = tid + NTH * i;
        if (u < UNITS) {
            int px = u / UPP, kg = u % UPP;
            int r = px / PXW, xp = px - r * PXW;
            u32x4 v = *(const u32x4*)(in_h +
                (size_t)((b * PH + y0 + r) * PXW + xp) * (NCHUNK * 32) + kg * 8);
            *(u32x4*)(ldsb + ((u * 16) ^ ((px & 7) << 4))) = v;
        }
    }
    __syncthreads();

    f32x4 acc[MT][NT];
#pragma unroll
    for (int mt = 0; mt < MT; ++mt)
#pragma unroll
        for (int nt = 0; nt < NT; ++nt)
            acc[mt][nt] = (f32x4){0.f, 0.f, 0.f, 0.f};

#pragma unroll
    for (int c = 0; c < NCHUNK; ++c) {
#pragma unroll
        for (int tap = 0; tap < 9; ++tap) {
            const int dy = tap / 3, dx = tap % 3;
            f16x8 afr[MT];
#pragma unroll
            for (int mt = 0; mt < MT; ++mt) {
                int px = (wm * MT + mt) * 16 + l15;
                int row = px >> XSH, x = px & (XW - 1);
                int pxl = (row + dy) * PXW + x + dx;
                int la = pxl * PXB + c * 64 + lk * 16;
                afr[mt] = *(const f16x8*)(ldsb + (la ^ ((pxl & 7) << 4)));
            }
#pragma unroll
            for (int nt = 0; nt < NT; ++nt) {
                int cout = wn * (NT * 16) + nt * 16 + l15;
                f16x8 bfr = *(const f16x8*)(wp + ((size_t)(cout * NCHUNK + c) * 9 + tap) * 32 + lk * 8);
#pragma unroll
                for (int mt = 0; mt < MT; ++mt)
                    acc[mt][nt] = __builtin_amdgcn_mfma_f32_16x16x32_f16(afr[mt], bfr, acc[mt][nt], 0, 0, 0);
            }
        }
    }

#pragma unroll
    for (int mt = 0; mt < MT; ++mt)
#pragma unroll
        for (int nt = 0; nt < NT; ++nt) {
            int cout = wn * (NT * 16) + nt * 16 + l15;
            float bv = bias[cout];
#pragma unroll
            for (int reg = 0; reg < 4; ++reg) {
                int px = (wm * MT + mt) * 16 + lk * 4 + reg;
                int row = px >> XSH, x = px & (XW - 1);
                int yim = y0 + row;
                float vv = acc[mt][nt][reg] + bv;
                size_t ah = ((size_t)(b * PH + yim + 1) * PXW + x + 1) * 128 + cout;
                if (mode == 1) vv = fmaxf(vv, 0.f);
                if (mode == 2) vv += (float)out_h[ah];
                if (mode == 3) {
                    vv += (float)skip_h[ah];
                    out2[((size_t)((b << XSH) + yim) << XSH | x) * 128 + cout] = (f16)vv;
                } else if (mode == 4) {
                    f16 hv = (f16)vv;
                    out_h[ah] = hv;
                    out2[ah] = hv;
                } else {
                    out_h[ah] = (f16)vv;
                }
            }
        }
}

// ---- fused spa+spe conv: blocks [0,g1) path 1, rest path 2 ----
// launch_bounds(512,6): cap VGPR ~85 so 3 blocks/CU (24 waves) fit with 50.7KB LDS
template<int PXW1, int XSH1, int ROWS1, int NCH1,
         int PXW2, int XSH2, int ROWS2, int NCH2, int WAVES>
__global__ __launch_bounds__(WAVES * 64, 6) void conv_dual(
    int g1,
    const f16* __restrict__ in1, const f16* __restrict__ wp1,
    const float* __restrict__ bi1, const f16* __restrict__ sk1,
    f16* __restrict__ o1h, f16* __restrict__ o1b,
    const f16* __restrict__ in2, const f16* __restrict__ wp2,
    const float* __restrict__ bi2, const f16* __restrict__ sk2,
    f16* __restrict__ o2h, f16* __restrict__ o2b,
    int mode) {
    constexpr int B1 = (ROWS1 + 2) * PXW1 * NCH1 * 64;
    constexpr int B2 = (ROWS2 + 2) * PXW2 * NCH2 * 64;
    constexpr int MAXB = B1 > B2 ? B1 : B2;
    __shared__ char ldsb[MAXB];
    int bx = blockIdx.x;
    if (bx < g1)
        conv_body<PXW1, XSH1, ROWS1, WAVES, NCH1>(bx, ldsb, in1, wp1, bi1, sk1, o1h, o1b, mode);
    else
        conv_body<PXW2, XSH2, ROWS2, WAVES, NCH2>(bx - g1, ldsb, in2, wp2, bi2, sk2, o2h, o2b, mode);
}

// both max pools (2x and 4x) in one launch, NHWC f16 C=128, 64x64 input
__global__ __launch_bounds__(256) void maxpool_both(
    const f16* __restrict__ in, f16* __restrict__ o2, f16* __restrict__ o4) {
    int i = blockIdx.x * 256 + threadIdx.x;
    if (i < 2097152) {
        int c = i & 127;
        int r = i >> 7;
        int x = r & 31; r >>= 5;
        int y = r & 31; r >>= 5;
        int b = r;
        float m = -3.402823466e38f;
        for (int dy = 0; dy < 2; ++dy)
            for (int dx = 0; dx < 2; ++dx)
                m = fmaxf(m, (float)in[((size_t)((b * 64 + y * 2 + dy)) * 64 + x * 2 + dx) * 128 + c]);
        o2[i] = (f16)m;
    } else {
        int j = i - 2097152;
        if (j < 524288) {
            int c = j & 127;
            int r = j >> 7;
            int x = r & 15; r >>= 4;
            int y = r & 15; r >>= 4;
            int b = r;
            float m = -3.402823466e38f;
            for (int dy = 0; dy < 4; ++dy)
                for (int dx = 0; dx < 4; ++dx)
                    m = fmaxf(m, (float)in[((size_t)((b * 64 + y * 4 + dy)) * 64 + x * 4 + dx) * 128 + c]);
            o4[j] = (f16)m;
        }
    }
}

// ---- Fused level(), all-MFMA, 16 queries/block, 256 threads (R14 version). ----
__global__ __launch_bounds__(256) void level_kernel(
    const f16* __restrict__ featT, int fh, int fw,
    const f16* __restrict__ guideT, int Hg, int Wg,
    const f16* __restrict__ glrT, int hl, int wl,
    int Hq, int Wq, int n_per_b,
    const f16* __restrict__ imw_h, const float* __restrict__ imb,
    const f16* __restrict__ w1h, const float* __restrict__ b1,
    const f16* __restrict__ w2h, const float* __restrict__ b2,
    const f16* __restrict__ f1h, const float* __restrict__ fb1,
    const f16* __restrict__ f2h, const float* __restrict__ fb2,
    int odim, int residual, int out_nchw,
    const float* __restrict__ lms,
    f16* __restrict__ out16, float* __restrict__ outf) {
    __shared__ char smem[58624];
    f16* s_inp  = (f16*)smem;            // [64][424]
    f16* s_pred = (f16*)smem;            // [128][136] overlay
    f16* s_h1   = (f16*)(smem + 34816);  // [128][72]
    f16* s_hh   = (f16*)smem;            // [16][72] overlay (after s_pred dead)
    f16* s_rec  = (f16*)(smem + 54272);  // [16][136]

    int tid = threadIdx.x;
    int b = blockIdx.x / n_per_b;
    int n0 = (blockIdx.x % n_per_b) * 16;
    float invHq = 1.0f / (float)Hq, invWq = 1.0f / (float)Wq;
    float invfh = 1.0f / (float)fh, invfw = 1.0f / (float)fw;
    int wave = tid >> 6, lane = tid & 63;
    int l15 = lane & 15, lk = lane >> 4;

    // ---- gather: build s_inp[64][424] fp16; row = (cidx, q), 4 threads/row ----
    {
        const int r64 = tid >> 2, t4 = tid & 3;
        const int cidx = r64 >> 4, q = r64 & 15;
        int n = n0 + q;
        int qy = n / Wq, qx = n - qy * Wq;
        float cy = -1.0f + (float)(2 * qy + 1) * invHq;
        float cx = -1.0f + (float)(2 * qx + 1) * invWq;
        float vxc = (cidx < 2) ? -1.0f : 1.0f;
        float vyc = (cidx & 1) ? 1.0f : -1.0f;
        float cy_ = cy + vxc * invfh;
        float cx_ = cx + vyc * invfw;
        int iy, ix; bool vf;
        nsamp(cy_, cx_, fh, fw, iy, ix, vf);
        const f16* fp = featT + ((size_t)(b * fh + iy) * fw + ix) * 128;
        int gy, gx; bool vg0;
        nsamp(cy, cx, Hg, Wg, gy, gx, vg0);
        const f16* gp = guideT + ((size_t)(b * Hg + gy) * Wg + gx) * 128;
        int ly, lx; bool vl;
        nsamp(cy_, cx_, hl, wl, ly, lx, vl);
        const f16* lp = glrT + ((size_t)(b * hl + ly) * wl + lx) * 128;
        f16* row = s_inp + r64 * 424;
        const u32x4 zz = (u32x4){0, 0, 0, 0};
#pragma unroll
        for (int e = 0; e < 4; ++e) {
            int d0 = t4 * 8 + e * 32;
            u32x4 av = vf ? *(const u32x4*)(fp + d0) : zz;
            u32x4 gv = vg0 ? *(const u32x4*)(gp + d0) : zz;
            u32x4 lv = vl ? *(const u32x4*)(lp + d0) : zz;
            *(u32x4*)(row + d0) = av;
            *(u32x4*)(row + 128 + d0) = gv;
            *(u32x4*)(row + 256 + d0) = lv;
        }
        if (t4 == 0) {
#pragma unroll
            for (int e = 0; e < 4; ++e)
                *(u32x4*)((char*)row + 768 + e * 16) = zz;
            float csy = vf ? (-1.0f + (float)(2 * iy + 1) * invfh) : 0.0f;
            float csx = vf ? (-1.0f + (float)(2 * ix + 1) * invfw) : 0.0f;
            row[384] = (f16)((cy - csy) * (float)fh);
            row[385] = (f16)((cx - csx) * (float)fw);
        }
    }
    __syncthreads();

    // ---- corner GEMM: 64x416 @ 416x256 ----
    f32x4 acc[4][4];
    {
#pragma unroll
        for (int mt = 0; mt < 4; ++mt)
#pragma unroll
            for (int nt = 0; nt < 4; ++nt)
                acc[mt][nt] = (f32x4){0.f, 0.f, 0.f, 0.f};
        int nbase = wave * 64;
#pragma unroll
        for (int ks = 0; ks < 13; ++ks) {
            f16x8 afr[4];
#pragma unroll
            for (int mt = 0; mt < 4; ++mt)
                afr[mt] = *(const f16x8*)((char*)s_inp + (mt * 16 + l15) * 848 + ks * 64 + lk * 16);
#pragma unroll
            for (int nt = 0; nt < 4; ++nt) {
                f16x8 bfr = *(const f16x8*)(imw_h + ((size_t)(nbase + nt * 16 + l15) * 13 + ks) * 32 + lk * 8);
#pragma unroll
                for (int mt = 0; mt < 4; ++mt)
                    acc[mt][nt] = __builtin_amdgcn_mfma_f32_16x16x32_f16(afr[mt], bfr, acc[mt][nt], 0, 0, 0);
            }
        }
    }
    __syncthreads();  // s_inp reads complete; region may be overlaid

    // ---- epilogue: bias + relu -> s_pred fp16 [qj][128] ----
    {
        int nbase = wave * 64;
#pragma unroll
        for (int nt = 0; nt < 4; ++nt) {
            int col = nbase + nt * 16 + l15;
            float bv = imb[col];
            int j_hi = col >> 7, d = col & 127;
#pragma unroll
            for (int mt = 0; mt < 4; ++mt)
#pragma unroll
                for (int reg = 0; reg < 4; ++reg) {
                    int row64 = mt * 16 + lk * 4 + reg;
                    int q = row64 & 15, cidx = row64 >> 4;
                    int qj = q * 8 + cidx * 2 + j_hi;
                    s_pred[qj * 136 + d] = (f16)fmaxf(acc[mt][nt][reg] + bv, 0.f);
                }
        }
    }
    __syncthreads();

    // ---- wg1: preds[128][128] @ w1[128][64] -> h1 fp16 [128][72] ----
    {
        f32x4 a1[8];
#pragma unroll
        for (int mt = 0; mt < 8; ++mt) a1[mt] = (f32x4){0.f, 0.f, 0.f, 0.f};
        int c1 = wave * 16 + l15;
#pragma unroll
        for (int ks = 0; ks < 4; ++ks) {
            f16x8 bfr = *(const f16x8*)(w1h + ((size_t)c1 * 4 + ks) * 32 + lk * 8);
#pragma unroll
            for (int mt = 0; mt < 8; ++mt) {
                f16x8 afr = *(const f16x8*)((char*)s_pred + (mt * 16 + l15) * 272 + ks * 64 + lk * 16);
                a1[mt] = __builtin_amdgcn_mfma_f32_16x16x32_f16(afr, bfr, a1[mt], 0, 0, 0);
            }
        }
        float bb1 = b1[c1];
#pragma unroll
        for (int mt = 0; mt < 8; ++mt)
#pragma unroll
            for (int reg = 0; reg < 4; ++reg) {
                int row = mt * 16 + lk * 4 + reg;
                s_h1[row * 72 + c1] = (f16)gelu_f(a1[mt][reg] + bb1);
            }
    }
    __syncthreads();

    // ---- wg2 + softmax over j + recon -> s_rec f16 [16][136] ----
    {
        f32x4 a2[8][2];
#pragma unroll
        for (int mt = 0; mt < 8; ++mt) {
            a2[mt][0] = (f32x4){0.f, 0.f, 0.f, 0.f};
            a2[mt][1] = (f32x4){0.f, 0.f, 0.f, 0.f};
        }
#pragma unroll
        for (int ks = 0; ks < 2; ++ks) {
#pragma unroll
            for (int nt = 0; nt < 2; ++nt) {
                int c2 = wave * 32 + nt * 16 + l15;
                f16x8 bfr = *(const f16x8*)(w2h + ((size_t)c2 * 2 + ks) * 32 + lk * 8);
#pragma unroll
                for (int mt = 0; mt < 8; ++mt) {
                    f16x8 afr = *(const f16x8*)((char*)s_h1 + (mt * 16 + l15) * 144 + ks * 64 + lk * 16);
                    a2[mt][nt] = __builtin_amdgcn_mfma_f32_16x16x32_f16(afr, bfr, a2[mt][nt], 0, 0, 0);
                }
            }
        }
        int qhalf = lk >> 1;
#pragma unroll
        for (int nt = 0; nt < 2; ++nt) {
            int col = wave * 32 + nt * 16 + l15;
            float bb2 = b2[col];
#pragma unroll
            for (int mt = 0; mt < 8; ++mt) {
                int q = mt * 2 + qhalf;
                float v[4];
                float mloc = -3.4e38f;
#pragma unroll
                for (int reg = 0; reg < 4; ++reg) {
                    v[reg] = a2[mt][nt][reg] + bb2;
                    mloc = fmaxf(mloc, v[reg]);
                }
                float mf = fmaxf(mloc, __shfl_xor(mloc, 16));
                float e[4], sl = 0.f;
#pragma unroll
                for (int reg = 0; reg < 4; ++reg) {
                    e[reg] = __expf(v[reg] - mf);
                    sl += e[reg];
                }
                float sf = sl + __shfl_xor(sl, 16);
                float inv = 1.0f / sf;
                float rp = 0.f;
#pragma unroll
                for (int reg = 0; reg < 4; ++reg) {
                    int row = mt * 16 + lk * 4 + reg;
                    rp += (float)s_pred[row * 136 + col] * e[reg];
                }
                rp *= inv;
                float rf = rp + __shfl_xor(rp, 16);
                if ((lk & 1) == 0) s_rec[q * 136 + col] = (f16)rf;
            }
        }
    }
    __syncthreads();  // s_pred/s_h1 dead; s_rec ready

    // ---- ffn1 (MFMA): rec[16][128] @ f1[128][64] -> s_hh[16][72] ----
    {
        f32x4 a1 = (f32x4){0.f, 0.f, 0.f, 0.f};
        int c1 = wave * 16 + l15;
#pragma unroll
        for (int ks = 0; ks < 4; ++ks) {
            f16x8 afr = *(const f16x8*)((char*)s_rec + l15 * 272 + ks * 64 + lk * 16);
            f16x8 bfr = *(const f16x8*)(f1h + ((size_t)c1 * 4 + ks) * 32 + lk * 8);
            a1 = __builtin_amdgcn_mfma_f32_16x16x32_f16(afr, bfr, a1, 0, 0, 0);
        }
        float bb = fb1[c1];
#pragma unroll
        for (int reg = 0; reg < 4; ++reg) {
            int row = lk * 4 + reg;
            s_hh[row * 72 + c1] = (f16)gelu_f(a1[reg] + bb);
        }
    }
    __syncthreads();

    // ---- ffn2 (MFMA): h[16][64] @ f2[64][odim] -> out ----
    if (!out_nchw) {
        f32x4 a2[2];
        a2[0] = (f32x4){0.f, 0.f, 0.f, 0.f};
        a2[1] = (f32x4){0.f, 0.f, 0.f, 0.f};
#pragma unroll
        for (int ks = 0; ks < 2; ++ks) {
            f16x8 afr = *(const f16x8*)((char*)s_hh + l15 * 144 + ks * 64 + lk * 16);
#pragma unroll
            for (int nt = 0; nt < 2; ++nt) {
                int col = wave * 32 + nt * 16 + l15;
                f16x8 bfr = *(const f16x8*)(f2h + ((size_t)col * 2 + ks) * 32 + lk * 8);
                a2[nt] = __builtin_amdgcn_mfma_f32_16x16x32_f16(afr, bfr, a2[nt], 0, 0, 0);
            }
        }
#pragma unroll
        for (int nt = 0; nt < 2; ++nt) {
            int col = wave * 32 + nt * 16 + l15;
            float bb = fb2[col];
#pragma unroll
            for (int reg = 0; reg < 4; ++reg) {
                int q = lk * 4 + reg;
                int n = n0 + q;
                int qy = n / Wq, qx = n - qy * Wq;
                float val = a2[nt][reg] + bb;
                if (residual) val += (float)s_rec[q * 136 + col];
                out16[((size_t)(b * Hq + qy) * Wq + qx) * 128 + col] = (f16)val;
            }
        }
    } else {
        if (wave < 2) {
            f32x4 a2 = (f32x4){0.f, 0.f, 0.f, 0.f};
#pragma unroll
            for (int ks = 0; ks < 2; ++ks) {
                f16x8 afr = *(const f16x8*)((char*)s_hh + l15 * 144 + ks * 64 + lk * 16);
                int col = wave * 16 + l15;
                f16x8 bfr = *(const f16x8*)(f2h + ((size_t)col * 2 + ks) * 32 + lk * 8);
                a2 = __builtin_amdgcn_mfma_f32_16x16x32_f16(afr, bfr, a2, 0, 0, 0);
            }
            int d = wave * 16 + l15;
            if (d < odim) {
                float bb = fb2[d];
#pragma unroll
                for (int reg = 0; reg < 4; ++reg) {
                    int q = lk * 4 + reg;
                    int n = n0 + q;
                    int qy = n / Wq, qx = n - qy * Wq;
                    size_t oi = (((size_t)b * odim + d) * Hq + qy) * Wq + qx;
                    outf[oi] = a2[reg] + bb + lms[oi];
                }
            }
        }
    }
}

// ---- workspace byte offsets ----
#define WPACK_B   0ull
#define CC_B      5529600ull
#define RH_B      14450688ull
#define TH_B      32292864ull
#define XH_B      50135040ull
#define G32_B     (TH_B)
#define G16_B     (TH_B + 4194304ull)
#define L1T_B     (TH_B + 5242880ull)
#define HR16_B    67977216ull
#define LVLW_B    101531648ull
#define L1IMW_B   (LVLW_B)
#define L1W1_B    (LVLW_B + 212992ull)
#define L1W2_B    (LVLW_B + 229376ull)
#define L1F1_B    (LVLW_B + 245760ull)
#define L1F2_B    (LVLW_B + 262144ull)
#define L2IMW_B   (LVLW_B + 278528ull)
#define L2W1_B    (LVLW_B + 491520ull)
#define L2W2_B    (LVLW_B + 507904ull)
#define L2F1_B    (LVLW_B + 524288ull)
#define L2F2_B    (LVLW_B + 540672ull)
#define SPE2_B    102088704ull
#define SPEIN_B   (SPE2_B)
#define X2_B      (SPE2_B + 331776ull)
#define R2_B      (SPE2_B + 1658880ull)
#define T2_B      (SPE2_B + 2985984ull)
#define LRSPE_B   (SPE2_B + 4313088ull)

extern "C" void kernel_launch(void* const* d_in, const int* in_sizes, int n_in,
                              void* d_out, int out_size, void* d_ws, size_t ws_size,
                              hipStream_t stream) {
    (void)in_sizes; (void)n_in; (void)out_size; (void)ws_size;
    const float* HR_MSI     = (const float*)d_in[0];
    const float* lms        = (const float*)d_in[1];
    const float* LR_HSI     = (const float*)d_in[2];
    const float* spa_head_w = (const float*)d_in[3];
    const float* spa_head_b = (const float*)d_in[4];
    const float* spa_res_w  = (const float*)d_in[5];
    const float* spa_res_b  = (const float*)d_in[6];
    const float* spa_tail_w = (const float*)d_in[7];
    const float* spa_tail_b = (const float*)d_in[8];
    const float* spe_head_w = (const float*)d_in[9];
    const float* spe_head_b = (const float*)d_in[10];
    const float* spe_res_w  = (const float*)d_in[11];
    const float* spe_res_b  = (const float*)d_in[12];
    const float* spe_tail_w = (const float*)d_in[13];
    const float* spe_tail_b = (const float*)d_in[14];
    const float* l1_w   = (const float*)d_in[15];
    const float* l1_b   = (const float*)d_in[16];
    const float* wg32_w1 = (const float*)d_in[17];
    const float* wg32_b1 = (const float*)d_in[18];
    const float* wg32_w2 = (const float*)d_in[19];
    const float* wg32_b2 = (const float*)d_in[20];
    const float* ffn32_w1 = (const float*)d_in[21];
    const float* ffn32_b1 = (const float*)d_in[22];
    const float* ffn32_w2 = (const float*)d_in[23];
    const float* ffn32_b2 = (const float*)d_in[24];
    const float* l2_w   = (const float*)d_in[25];
    const float* l2_b   = (const float*)d_in[26];
    const float* wg64_w1 = (const float*)d_in[27];
    const float* wg64_b1 = (const float*)d_in[28];
    const float* wg64_w2 = (const float*)d_in[29];
    const float* wg64_b2 = (const float*)d_in[30];
    const float* ffn64_w1 = (const float*)d_in[31];
    const float* ffn64_b1 = (const float*)d_in[32];
    const float* ffn64_w2 = (const float*)d_in[33];
    const float* ffn64_b2 = (const float*)d_in[34];

    char* ws = (char*)d_ws;
    f16* Wp      = (f16*)(ws + WPACK_B);
    f16* Cc      = (f16*)(ws + CC_B);
    f16* SPEin   = (f16*)(ws + SPEIN_B);
    f16* X2h     = (f16*)(ws + X2_B);
    f16* R2h     = (f16*)(ws + R2_B);
    f16* T2h     = (f16*)(ws + T2_B);
    f16* lrspe16 = (f16*)(ws + LRSPE_B);
    f16* Rh      = (f16*)(ws + RH_B);
    f16* Xh      = (f16*)(ws + XH_B);
    f16* Th      = (f16*)(ws + TH_B);
    f16* g32T    = (f16*)(ws + G32_B);
    f16* g16T    = (f16*)(ws + G16_B);
    f16* l1T16   = (f16*)(ws + L1T_B);
    f16* hr16    = (f16*)(ws + HR16_B);
    f16* lvlw    = (f16*)(ws + LVLW_B);
    f16* l1imw = (f16*)(ws + L1IMW_B);
    f16* l1w1  = (f16*)(ws + L1W1_B);
    f16* l1w2  = (f16*)(ws + L1W2_B);
    f16* l1f1  = (f16*)(ws + L1F1_B);
    f16* l1f2  = (f16*)(ws + L1F2_B);
    f16* l2imw = (f16*)(ws + L2IMW_B);
    f16* l2w1  = (f16*)(ws + L2W1_B);
    f16* l2w2  = (f16*)(ws + L2W2_B);
    f16* l2f1  = (f16*)(ws + L2F1_B);
    f16* l2f2  = (f16*)(ws + L2F2_B);

    // zero padded fp16 regions (borders + never-written channels must be 0)
    hipMemsetAsync(ws + CC_B, 0, 8921088ull, stream);
    hipMemsetAsync(ws + RH_B, 0, 53526528ull, stream);
    hipMemsetAsync(ws + SPE2_B, 0, 5361664ull, stream);

    // pack all conv weights (one launch) and all level weights (one launch)
    pack_w_all<<<10800, 256, 0, stream>>>(spa_head_w, spa_res_w, spa_tail_w,
                                          spe_head_w, spe_res_w, spe_tail_w, Wp);
    pack_lvl_all<<<1064, 256, 0, stream>>>(l1_w, wg32_w1, wg32_w2, ffn32_w1, ffn32_w2,
                                           l2_w, wg64_w1, wg64_w2, ffn64_w1, ffn64_w2,
                                           lvlw);

    // ---- build padded inputs (disjoint regions) ----
    build_cc<<<8704, 256, 0, stream>>>(HR_MSI, lms, Cc, 16 * 64 * 64 * 34);
    build_spe<<<496, 256, 0, stream>>>(LR_HSI, SPEin, 16 * 16 * 16 * 31);

    // ---- fused spa+spe EDSR: spa ROWS=1 (grid 1024, 3 blocks/CU), spe ROWS=2 ----
    conv_dual<66, 6, 1, 2, 18, 4, 2, 1, 8><<<1152, 512, 0, stream>>>(
        1024,
        Cc, Wp + 0, spa_head_b, nullptr, Xh, Rh,
        SPEin, Wp + 1400832, spe_head_b, nullptr, X2h, R2h, 4);
    for (int i = 0; i < 4; ++i) {
        conv_dual<66, 6, 1, 4, 18, 4, 2, 4, 8><<<1152, 512, 0, stream>>>(
            1024,
            Rh, Wp + 73728 + (size_t)(2 * i) * 147456, spa_res_b + 2 * i * 128, nullptr, Th, nullptr,
            R2h, Wp + 1437696 + (size_t)(2 * i) * 147456, spe_res_b + 2 * i * 128, nullptr, T2h, nullptr, 1);
        conv_dual<66, 6, 1, 4, 18, 4, 2, 4, 8><<<1152, 512, 0, stream>>>(
            1024,
            Th, Wp + 73728 + (size_t)(2 * i + 1) * 147456, spa_res_b + (2 * i + 1) * 128, nullptr, Rh, nullptr,
            T2h, Wp + 1437696 + (size_t)(2 * i + 1) * 147456, spe_res_b + (2 * i + 1) * 128, nullptr, R2h, nullptr, 2);
    }
    conv_dual<66, 6, 1, 4, 18, 4, 2, 4, 8><<<1152, 512, 0, stream>>>(
        1024,
        Rh, Wp + 1253376, spa_tail_b, Xh, nullptr, hr16,
        R2h, Wp + 2617344, spe_tail_b, X2h, nullptr, lrspe16, 3);

    // ---- both max pools in one launch ----
    maxpool_both<<<10240, 256, 0, stream>>>(hr16, g32T, g16T);

    // ---- level 1: 32x32 queries, 16 q/block -> l1T16 f16 ----
    level_kernel<<<1024, 256, 0, stream>>>(
        lrspe16, 16, 16, g32T, 32, 32, g16T, 16, 16,
        32, 32, 64,
        l1imw, l1_b, l1w1, wg32_b1, l1w2, wg32_b2,
        l1f1, ffn32_b1, l1f2, ffn32_b2,
        128, 1, 0, nullptr, l1T16, nullptr);

    // ---- level 2: 64x64 queries, 16 q/block, + lms, fp32 NCHW to d_out ----
    level_kernel<<<4096, 256, 0, stream>>>(
        l1T16, 32, 32, hr16, 64, 64, g32T, 32, 32,
        64, 64, 256,
        l2imw, l2_b, l2w1, wg64_b1, l2w2, wg64_b2,
        l2f1, ffn64_b1, l2f2, ffn64_b2,
        31, 0, 1, lms, nullptr, (float*)d_out);
}

// Round 17
// 914.287 us; speedup vs baseline: 1.2859x; 1.2859x over previous
//
#include <hip/hip_runtime.h>
#include <math.h>

typedef _Float16 f16;
typedef __attribute__((ext_vector_type(4))) _Float16 f16x4;
typedef __attribute__((ext_vector_type(8))) _Float16 f16x8;
typedef __attribute__((ext_vector_type(4))) float f32x4;
typedef __attribute__((ext_vector_type(4))) unsigned int u32x4;

// exact-GELU via Abramowitz-Stegun 7.1.26 erf (|err| <= 1.5e-7)
__device__ __forceinline__ float gelu_f(float x) {
    float xs = x * 0.70710678118654752440f;
    float ax = fabsf(xs);
    float t = __builtin_amdgcn_rcpf(1.0f + 0.3275911f * ax);
    float p = t * (0.254829592f + t * (-0.284496736f + t * (1.421413741f +
              t * (-1.453152027f + t * 1.061405429f))));
    float erfv = 1.0f - p * __expf(-ax * ax);
    erfv = copysignf(erfv, xs);
    return 0.5f * x * (1.0f + erfv);
}

__device__ __forceinline__ void nsamp(float cy, float cx, int hi, int wi,
                                      int& iy, int& ix, bool& valid) {
    float fy = rintf(((cy + 1.0f) * (float)hi - 1.0f) * 0.5f);
    float fx = rintf(((cx + 1.0f) * (float)wi - 1.0f) * 0.5f);
    valid = (fy >= 0.0f) && (fy < (float)hi) && (fx >= 0.0f) && (fx < (float)wi);
    iy = (int)fminf(fmaxf(fy, 0.0f), (float)(hi - 1));
    ix = (int)fminf(fmaxf(fx, 0.0f), (float)(wi - 1));
}

// ---- ALL conv weight packs in one launch: OIHW fp32 -> [cout][chunk][tap][ci32] f16 ----
__global__ __launch_bounds__(256) void pack_w_all(
    const float* __restrict__ s0, const float* __restrict__ s1,
    const float* __restrict__ s2, const float* __restrict__ s3,
    const float* __restrict__ s4, const float* __restrict__ s5,
    f16* __restrict__ dst) {
    int i = blockIdx.x * 256 + threadIdx.x;
    const float* src; int Cin, NCH, base;
    if (i < 73728)        { src = s0; Cin = 34;  NCH = 2; base = 0; }
    else if (i < 1253376) { src = s1; Cin = 128; NCH = 4; base = 73728; }
    else if (i < 1400832) { src = s2; Cin = 128; NCH = 4; base = 1253376; }
    else if (i < 1437696) { src = s3; Cin = 31;  NCH = 1; base = 1400832; }
    else if (i < 2617344) { src = s4; Cin = 128; NCH = 4; base = 1437696; }
    else if (i < 2764800) { src = s5; Cin = 128; NCH = 4; base = 2617344; }
    else return;
    int j = i - base;
    int ci = j & 31;
    int tap = (j >> 5) % 9;
    int q = j / 288;
    int chunk = q % NCH;
    int q2 = q / NCH;
    int cout = q2 & 127;
    int conv = q2 >> 7;
    int cin = chunk * 32 + ci;
    float v = (cin < Cin) ? src[((size_t)(conv * 128 + cout) * Cin + cin) * 9 + tap] : 0.f;
    dst[i] = (f16)v;
}

// ---- ALL level MLP packs in one launch: fp32 [K][N] -> f16 [N][NC][32] ----
__global__ __launch_bounds__(256) void pack_lvl_all(
    const float* __restrict__ p0, const float* __restrict__ p1,
    const float* __restrict__ p2, const float* __restrict__ p3,
    const float* __restrict__ p4, const float* __restrict__ p5,
    const float* __restrict__ p6, const float* __restrict__ p7,
    const float* __restrict__ p8, const float* __restrict__ p9,
    f16* __restrict__ dst) {
    int i = blockIdx.x * 256 + threadIdx.x;
    const float* src; int Ksrc, N, NC, base;
    if (i < 106496)      { src = p0; Ksrc = 386; N = 256; NC = 13; base = 0; }
    else if (i < 114688) { src = p1; Ksrc = 128; N = 64;  NC = 4;  base = 106496; }
    else if (i < 122880) { src = p2; Ksrc = 64;  N = 128; NC = 2;  base = 114688; }
    else if (i < 131072) { src = p3; Ksrc = 128; N = 64;  NC = 4;  base = 122880; }
    else if (i < 139264) { src = p4; Ksrc = 64;  N = 128; NC = 2;  base = 131072; }
    else if (i < 245760) { src = p5; Ksrc = 386; N = 256; NC = 13; base = 139264; }
    else if (i < 253952) { src = p6; Ksrc = 128; N = 64;  NC = 4;  base = 245760; }
    else if (i < 262144) { src = p7; Ksrc = 64;  N = 128; NC = 2;  base = 253952; }
    else if (i < 270336) { src = p8; Ksrc = 128; N = 64;  NC = 4;  base = 262144; }
    else if (i < 272320) { src = p9; Ksrc = 64;  N = 31;  NC = 2;  base = 270336; }
    else return;
    int j = i - base;
    int kk = j & 31;
    int c = (j >> 5) % NC;
    int n = j / (32 * NC);
    int k = c * 32 + kk;
    dst[i] = (f16)((k < Ksrc) ? src[(size_t)k * N + n] : 0.f);
}

// concat(HR_MSI, lms) -> padded NHWC fp16 [16][66][66][64]
__global__ __launch_bounds__(256) void build_cc(
    const float* __restrict__ msi, const float* __restrict__ lms,
    f16* __restrict__ out, int total) {
    int i = blockIdx.x * 256 + threadIdx.x;
    if (i >= total) return;
    int ch = i % 34;
    int p = i / 34;
    int x = p & 63, y = (p >> 6) & 63, b = p >> 12;
    float v = (ch < 3) ? msi[(((size_t)(b * 3 + ch) << 6) + y << 6) + x]
                       : lms[(((size_t)(b * 31 + ch - 3) << 6) + y << 6) + x];
    out[((size_t)(b * 66 + y + 1) * 66 + x + 1) * 64 + ch] = v;
}

// LR_HSI -> padded NHWC fp16 [16][18][18][32]
__global__ __launch_bounds__(256) void build_spe(
    const float* __restrict__ in, f16* __restrict__ out, int total) {
    int i = blockIdx.x * 256 + threadIdx.x;
    if (i >= total) return;
    int ch = i % 31;
    int p = i / 31;
    int x = p & 15, y = (p >> 4) & 15, b = p >> 8;
    out[((size_t)(b * 18 + y + 1) * 18 + x + 1) * 32 + ch] =
        (f16)in[(((size_t)(b * 31 + ch) << 4) + y << 4) + x];
}

// ---- implicit-GEMM conv3x3 body: whole tile staged once, 1 barrier ----
template<int PXW, int XSH, int ROWS, int WAVES, int NCHUNK>
__device__ __forceinline__ void conv_body(
    int bx, char* ldsb,
    const f16* __restrict__ in_h,
    const f16* __restrict__ wp, const float* __restrict__ bias,
    const f16* __restrict__ skip_h, f16* __restrict__ out_h,
    f16* __restrict__ out2, int mode) {
    constexpr int XW = 1 << XSH;
    constexpr int PH = XW + 2;
    constexpr int NPX = (ROWS + 2) * PXW;
    constexpr int UPP = NCHUNK * 4;
    constexpr int UNITS = NPX * UPP;
    constexpr int NTH = WAVES * 64;
    constexpr int ITER = (UNITS + NTH - 1) / NTH;
    constexpr int WN = WAVES / 2;
    constexpr int NT = 8 / WN;
    constexpr int MT = (ROWS << XSH) >> 5;
    constexpr int PXB = NCHUNK * 64;

    int tid = threadIdx.x;
    constexpr int NYB = XW / ROWS;
    int b = bx / NYB;
    int y0 = (bx % NYB) * ROWS;
    int wave = tid >> 6, lane = tid & 63;
    int wm = wave / WN, wn = wave % WN;
    int l15 = lane & 15, lk = lane >> 4;

#pragma unroll
    for (int i = 0; i < ITER; ++i) {
        int u = tid + NTH * i;
        if (u < UNITS) {
            int px = u / UPP, kg = u % UPP;
            int r = px / PXW, xp = px - r * PXW;
            u32x4 v = *(const u32x4*)(in_h +
                (size_t)((b * PH + y0 + r) * PXW + xp) * (NCHUNK * 32) + kg * 8);
            *(u32x4*)(ldsb + ((u * 16) ^ ((px & 7) << 4))) = v;
        }
    }
    __syncthreads();

    f32x4 acc[MT][NT];
#pragma unroll
    for (int mt = 0; mt < MT; ++mt)
#pragma unroll
        for (int nt = 0; nt < NT; ++nt)
            acc[mt][nt] = (f32x4){0.f, 0.f, 0.f, 0.f};

#pragma unroll
    for (int c = 0; c < NCHUNK; ++c) {
#pragma unroll
        for (int tap = 0; tap < 9; ++tap) {
            const int dy = tap / 3, dx = tap % 3;
            f16x8 afr[MT];
#pragma unroll
            for (int mt = 0; mt < MT; ++mt) {
                int px = (wm * MT + mt) * 16 + l15;
                int row = px >> XSH, x = px & (XW - 1);
                int pxl = (row + dy) * PXW + x + dx;
                int la = pxl * PXB + c * 64 + lk * 16;
                afr[mt] = *(const f16x8*)(ldsb + (la ^ ((pxl & 7) << 4)));
            }
#pragma unroll
            for (int nt = 0; nt < NT; ++nt) {
                int cout = wn * (NT * 16) + nt * 16 + l15;
                f16x8 bfr = *(const f16x8*)(wp + ((size_t)(cout * NCHUNK + c) * 9 + tap) * 32 + lk * 8);
#pragma unroll
                for (int mt = 0; mt < MT; ++mt)
                    acc[mt][nt] = __builtin_amdgcn_mfma_f32_16x16x32_f16(afr[mt], bfr, acc[mt][nt], 0, 0, 0);
            }
        }
    }

#pragma unroll
    for (int mt = 0; mt < MT; ++mt)
#pragma unroll
        for (int nt = 0; nt < NT; ++nt) {
            int cout = wn * (NT * 16) + nt * 16 + l15;
            float bv = bias[cout];
#pragma unroll
            for (int reg = 0; reg < 4; ++reg) {
                int px = (wm * MT + mt) * 16 + lk * 4 + reg;
                int row = px >> XSH, x = px & (XW - 1);
                int yim = y0 + row;
                float vv = acc[mt][nt][reg] + bv;
                size_t ah = ((size_t)(b * PH + yim + 1) * PXW + x + 1) * 128 + cout;
                if (mode == 1) vv = fmaxf(vv, 0.f);
                if (mode == 2) vv += (float)out_h[ah];
                if (mode == 3) {
                    vv += (float)skip_h[ah];
                    out2[((size_t)((b << XSH) + yim) << XSH | x) * 128 + cout] = (f16)vv;
                } else if (mode == 4) {
                    f16 hv = (f16)vv;
                    out_h[ah] = hv;
                    out2[ah] = hv;
                } else {
                    out_h[ah] = (f16)vv;
                }
            }
        }
}

// ---- fused spa+spe conv ----
template<int PXW1, int XSH1, int ROWS1, int NCH1,
         int PXW2, int XSH2, int ROWS2, int NCH2, int WAVES>
__global__ __launch_bounds__(WAVES * 64, 4) void conv_dual(
    int g1,
    const f16* __restrict__ in1, const f16* __restrict__ wp1,
    const float* __restrict__ bi1, const f16* __restrict__ sk1,
    f16* __restrict__ o1h, f16* __restrict__ o1b,
    const f16* __restrict__ in2, const f16* __restrict__ wp2,
    const float* __restrict__ bi2, const f16* __restrict__ sk2,
    f16* __restrict__ o2h, f16* __restrict__ o2b,
    int mode) {
    constexpr int B1 = (ROWS1 + 2) * PXW1 * NCH1 * 64;
    constexpr int B2 = (ROWS2 + 2) * PXW2 * NCH2 * 64;
    constexpr int MAXB = B1 > B2 ? B1 : B2;
    __shared__ char ldsb[MAXB];
    int bx = blockIdx.x;
    if (bx < g1)
        conv_body<PXW1, XSH1, ROWS1, WAVES, NCH1>(bx, ldsb, in1, wp1, bi1, sk1, o1h, o1b, mode);
    else
        conv_body<PXW2, XSH2, ROWS2, WAVES, NCH2>(bx - g1, ldsb, in2, wp2, bi2, sk2, o2h, o2b, mode);
}

// both max pools (2x and 4x) in one launch, NHWC f16 C=128, 64x64 input
__global__ __launch_bounds__(256) void maxpool_both(
    const f16* __restrict__ in, f16* __restrict__ o2, f16* __restrict__ o4) {
    int i = blockIdx.x * 256 + threadIdx.x;
    if (i < 2097152) {
        int c = i & 127;
        int r = i >> 7;
        int x = r & 31; r >>= 5;
        int y = r & 31; r >>= 5;
        int b = r;
        float m = -3.402823466e38f;
        for (int dy = 0; dy < 2; ++dy)
            for (int dx = 0; dx < 2; ++dx)
                m = fmaxf(m, (float)in[((size_t)((b * 64 + y * 2 + dy)) * 64 + x * 2 + dx) * 128 + c]);
        o2[i] = (f16)m;
    } else {
        int j = i - 2097152;
        if (j < 524288) {
            int c = j & 127;
            int r = j >> 7;
            int x = r & 15; r >>= 4;
            int y = r & 15; r >>= 4;
            int b = r;
            float m = -3.402823466e38f;
            for (int dy = 0; dy < 4; ++dy)
                for (int dx = 0; dx < 4; ++dx)
                    m = fmaxf(m, (float)in[((size_t)((b * 64 + y * 4 + dy)) * 64 + x * 4 + dx) * 128 + c]);
            o4[j] = (f16)m;
        }
    }
}

// ---- Fused level(), all-MFMA, 16 queries/block, 256 threads (R14 version). ----
__global__ __launch_bounds__(256) void level_kernel(
    const f16* __restrict__ featT, int fh, int fw,
    const f16* __restrict__ guideT, int Hg, int Wg,
    const f16* __restrict__ glrT, int hl, int wl,
    int Hq, int Wq, int n_per_b,
    const f16* __restrict__ imw_h, const float* __restrict__ imb,
    const f16* __restrict__ w1h, const float* __restrict__ b1,
    const f16* __restrict__ w2h, const float* __restrict__ b2,
    const f16* __restrict__ f1h, const float* __restrict__ fb1,
    const f16* __restrict__ f2h, const float* __restrict__ fb2,
    int odim, int residual, int out_nchw,
    const float* __restrict__ lms,
    f16* __restrict__ out16, float* __restrict__ outf) {
    __shared__ char smem[58624];
    f16* s_inp  = (f16*)smem;            // [64][424]
    f16* s_pred = (f16*)smem;            // [128][136] overlay
    f16* s_h1   = (f16*)(smem + 34816);  // [128][72]
    f16* s_hh   = (f16*)smem;            // [16][72] overlay (after s_pred dead)
    f16* s_rec  = (f16*)(smem + 54272);  // [16][136]

    int tid = threadIdx.x;
    int b = blockIdx.x / n_per_b;
    int n0 = (blockIdx.x % n_per_b) * 16;
    float invHq = 1.0f / (float)Hq, invWq = 1.0f / (float)Wq;
    float invfh = 1.0f / (float)fh, invfw = 1.0f / (float)fw;
    int wave = tid >> 6, lane = tid & 63;
    int l15 = lane & 15, lk = lane >> 4;

    // ---- gather: build s_inp[64][424] fp16; row = (cidx, q), 4 threads/row ----
    {
        const int r64 = tid >> 2, t4 = tid & 3;
        const int cidx = r64 >> 4, q = r64 & 15;
        int n = n0 + q;
        int qy = n / Wq, qx = n - qy * Wq;
        float cy = -1.0f + (float)(2 * qy + 1) * invHq;
        float cx = -1.0f + (float)(2 * qx + 1) * invWq;
        float vxc = (cidx < 2) ? -1.0f : 1.0f;
        float vyc = (cidx & 1) ? 1.0f : -1.0f;
        float cy_ = cy + vxc * invfh;
        float cx_ = cx + vyc * invfw;
        int iy, ix; bool vf;
        nsamp(cy_, cx_, fh, fw, iy, ix, vf);
        const f16* fp = featT + ((size_t)(b * fh + iy) * fw + ix) * 128;
        int gy, gx; bool vg0;
        nsamp(cy, cx, Hg, Wg, gy, gx, vg0);
        const f16* gp = guideT + ((size_t)(b * Hg + gy) * Wg + gx) * 128;
        int ly, lx; bool vl;
        nsamp(cy_, cx_, hl, wl, ly, lx, vl);
        const f16* lp = glrT + ((size_t)(b * hl + ly) * wl + lx) * 128;
        f16* row = s_inp + r64 * 424;
        const u32x4 zz = (u32x4){0, 0, 0, 0};
#pragma unroll
        for (int e = 0; e < 4; ++e) {
            int d0 = t4 * 8 + e * 32;
            u32x4 av = vf ? *(const u32x4*)(fp + d0) : zz;
            u32x4 gv = vg0 ? *(const u32x4*)(gp + d0) : zz;
            u32x4 lv = vl ? *(const u32x4*)(lp + d0) : zz;
            *(u32x4*)(row + d0) = av;
            *(u32x4*)(row + 128 + d0) = gv;
            *(u32x4*)(row + 256 + d0) = lv;
        }
        if (t4 == 0) {
#pragma unroll
            for (int e = 0; e < 4; ++e)
                *(u32x4*)((char*)row + 768 + e * 16) = zz;
            float csy = vf ? (-1.0f + (float)(2 * iy + 1) * invfh) : 0.0f;
            float csx = vf ? (-1.0f + (float)(2 * ix + 1) * invfw) : 0.0f;
            row[384] = (f16)((cy - csy) * (float)fh);
            row[385] = (f16)((cx - csx) * (float)fw);
        }
    }
    __syncthreads();

    // ---- corner GEMM: 64x416 @ 416x256 ----
    f32x4 acc[4][4];
    {
#pragma unroll
        for (int mt = 0; mt < 4; ++mt)
#pragma unroll
            for (int nt = 0; nt < 4; ++nt)
                acc[mt][nt] = (f32x4){0.f, 0.f, 0.f, 0.f};
        int nbase = wave * 64;
#pragma unroll
        for (int ks = 0; ks < 13; ++ks) {
            f16x8 afr[4];
#pragma unroll
            for (int mt = 0; mt < 4; ++mt)
                afr[mt] = *(const f16x8*)((char*)s_inp + (mt * 16 + l15) * 848 + ks * 64 + lk * 16);
#pragma unroll
            for (int nt = 0; nt < 4; ++nt) {
                f16x8 bfr = *(const f16x8*)(imw_h + ((size_t)(nbase + nt * 16 + l15) * 13 + ks) * 32 + lk * 8);
#pragma unroll
                for (int mt = 0; mt < 4; ++mt)
                    acc[mt][nt] = __builtin_amdgcn_mfma_f32_16x16x32_f16(afr[mt], bfr, acc[mt][nt], 0, 0, 0);
            }
        }
    }
    __syncthreads();  // s_inp reads complete; region may be overlaid

    // ---- epilogue: bias + relu -> s_pred fp16 [qj][128] ----
    {
        int nbase = wave * 64;
#pragma unroll
        for (int nt = 0; nt < 4; ++nt) {
            int col = nbase + nt * 16 + l15;
            float bv = imb[col];
            int j_hi = col >> 7, d = col & 127;
#pragma unroll
            for (int mt = 0; mt < 4; ++mt)
#pragma unroll
                for (int reg = 0; reg < 4; ++reg) {
                    int row64 = mt * 16 + lk * 4 + reg;
                    int q = row64 & 15, cidx = row64 >> 4;
                    int qj = q * 8 + cidx * 2 + j_hi;
                    s_pred[qj * 136 + d] = (f16)fmaxf(acc[mt][nt][reg] + bv, 0.f);
                }
        }
    }
    __syncthreads();

    // ---- wg1: preds[128][128] @ w1[128][64] -> h1 fp16 [128][72] ----
    {
        f32x4 a1[8];
#pragma unroll
        for (int mt = 0; mt < 8; ++mt) a1[mt] = (f32x4){0.f, 0.f, 0.f, 0.f};
        int c1 = wave * 16 + l15;
#pragma unroll
        for (int ks = 0; ks < 4; ++ks) {
            f16x8 bfr = *(const f16x8*)(w1h + ((size_t)c1 * 4 + ks) * 32 + lk * 8);
#pragma unroll
            for (int mt = 0; mt < 8; ++mt) {
                f16x8 afr = *(const f16x8*)((char*)s_pred + (mt * 16 + l15) * 272 + ks * 64 + lk * 16);
                a1[mt] = __builtin_amdgcn_mfma_f32_16x16x32_f16(afr, bfr, a1[mt], 0, 0, 0);
            }
        }
        float bb1 = b1[c1];
#pragma unroll
        for (int mt = 0; mt < 8; ++mt)
#pragma unroll
            for (int reg = 0; reg < 4; ++reg) {
                int row = mt * 16 + lk * 4 + reg;
                s_h1[row * 72 + c1] = (f16)gelu_f(a1[mt][reg] + bb1);
            }
    }
    __syncthreads();

    // ---- wg2 + softmax over j + recon -> s_rec f16 [16][136] ----
    {
        f32x4 a2[8][2];
#pragma unroll
        for (int mt = 0; mt < 8; ++mt) {
            a2[mt][0] = (f32x4){0.f, 0.f, 0.f, 0.f};
            a2[mt][1] = (f32x4){0.f, 0.f, 0.f, 0.f};
        }
#pragma unroll
        for (int ks = 0; ks < 2; ++ks) {
#pragma unroll
            for (int nt = 0; nt < 2; ++nt) {
                int c2 = wave * 32 + nt * 16 + l15;
                f16x8 bfr = *(const f16x8*)(w2h + ((size_t)c2 * 2 + ks) * 32 + lk * 8);
#pragma unroll
                for (int mt = 0; mt < 8; ++mt) {
                    f16x8 afr = *(const f16x8*)((char*)s_h1 + (mt * 16 + l15) * 144 + ks * 64 + lk * 16);
                    a2[mt][nt] = __builtin_amdgcn_mfma_f32_16x16x32_f16(afr, bfr, a2[mt][nt], 0, 0, 0);
                }
            }
        }
        int qhalf = lk >> 1;
#pragma unroll
        for (int nt = 0; nt < 2; ++nt) {
            int col = wave * 32 + nt * 16 + l15;
            float bb2 = b2[col];
#pragma unroll
            for (int mt = 0; mt < 8; ++mt) {
                int q = mt * 2 + qhalf;
                float v[4];
                float mloc = -3.4e38f;
#pragma unroll
                for (int reg = 0; reg < 4; ++reg) {
                    v[reg] = a2[mt][nt][reg] + bb2;
                    mloc = fmaxf(mloc, v[reg]);
                }
                float mf = fmaxf(mloc, __shfl_xor(mloc, 16));
                float e[4], sl = 0.f;
#pragma unroll
                for (int reg = 0; reg < 4; ++reg) {
                    e[reg] = __expf(v[reg] - mf);
                    sl += e[reg];
                }
                float sf = sl + __shfl_xor(sl, 16);
                float inv = 1.0f / sf;
                float rp = 0.f;
#pragma unroll
                for (int reg = 0; reg < 4; ++reg) {
                    int row = mt * 16 + lk * 4 + reg;
                    rp += (float)s_pred[row * 136 + col] * e[reg];
                }
                rp *= inv;
                float rf = rp + __shfl_xor(rp, 16);
                if ((lk & 1) == 0) s_rec[q * 136 + col] = (f16)rf;
            }
        }
    }
    __syncthreads();  // s_pred/s_h1 dead; s_rec ready

    // ---- ffn1 (MFMA): rec[16][128] @ f1[128][64] -> s_hh[16][72] ----
    {
        f32x4 a1 = (f32x4){0.f, 0.f, 0.f, 0.f};
        int c1 = wave * 16 + l15;
#pragma unroll
        for (int ks = 0; ks < 4; ++ks) {
            f16x8 afr = *(const f16x8*)((char*)s_rec + l15 * 272 + ks * 64 + lk * 16);
            f16x8 bfr = *(const f16x8*)(f1h + ((size_t)c1 * 4 + ks) * 32 + lk * 8);
            a1 = __builtin_amdgcn_mfma_f32_16x16x32_f16(afr, bfr, a1, 0, 0, 0);
        }
        float bb = fb1[c1];
#pragma unroll
        for (int reg = 0; reg < 4; ++reg) {
            int row = lk * 4 + reg;
            s_hh[row * 72 + c1] = (f16)gelu_f(a1[reg] + bb);
        }
    }
    __syncthreads();

    // ---- ffn2 (MFMA): h[16][64] @ f2[64][odim] -> out ----
    if (!out_nchw) {
        f32x4 a2[2];
        a2[0] = (f32x4){0.f, 0.f, 0.f, 0.f};
        a2[1] = (f32x4){0.f, 0.f, 0.f, 0.f};
#pragma unroll
        for (int ks = 0; ks < 2; ++ks) {
            f16x8 afr = *(const f16x8*)((char*)s_hh + l15 * 144 + ks * 64 + lk * 16);
#pragma unroll
            for (int nt = 0; nt < 2; ++nt) {
                int col = wave * 32 + nt * 16 + l15;
                f16x8 bfr = *(const f16x8*)(f2h + ((size_t)col * 2 + ks) * 32 + lk * 8);
                a2[nt] = __builtin_amdgcn_mfma_f32_16x16x32_f16(afr, bfr, a2[nt], 0, 0, 0);
            }
        }
#pragma unroll
        for (int nt = 0; nt < 2; ++nt) {
            int col = wave * 32 + nt * 16 + l15;
            float bb = fb2[col];
#pragma unroll
            for (int reg = 0; reg < 4; ++reg) {
                int q = lk * 4 + reg;
                int n = n0 + q;
                int qy = n / Wq, qx = n - qy * Wq;
                float val = a2[nt][reg] + bb;
                if (residual) val += (float)s_rec[q * 136 + col];
                out16[((size_t)(b * Hq + qy) * Wq + qx) * 128 + col] = (f16)val;
            }
        }
    } else {
        if (wave < 2) {
            f32x4 a2 = (f32x4){0.f, 0.f, 0.f, 0.f};
#pragma unroll
            for (int ks = 0; ks < 2; ++ks) {
                f16x8 afr = *(const f16x8*)((char*)s_hh + l15 * 144 + ks * 64 + lk * 16);
                int col = wave * 16 + l15;
                f16x8 bfr = *(const f16x8*)(f2h + ((size_t)col * 2 + ks) * 32 + lk * 8);
                a2 = __builtin_amdgcn_mfma_f32_16x16x32_f16(afr, bfr, a2, 0, 0, 0);
            }
            int d = wave * 16 + l15;
            if (d < odim) {
                float bb = fb2[d];
#pragma unroll
                for (int reg = 0; reg < 4; ++reg) {
                    int q = lk * 4 + reg;
                    int n = n0 + q;
                    int qy = n / Wq, qx = n - qy * Wq;
                    size_t oi = (((size_t)b * odim + d) * Hq + qy) * Wq + qx;
                    outf[oi] = a2[reg] + bb + lms[oi];
                }
            }
        }
    }
}

// ---- workspace byte offsets ----
#define WPACK_B   0ull
#define CC_B      5529600ull
#define RH_B      14450688ull
#define TH_B      32292864ull
#define XH_B      50135040ull
#define G32_B     (TH_B)
#define G16_B     (TH_B + 4194304ull)
#define L1T_B     (TH_B + 5242880ull)
#define HR16_B    67977216ull
#define LVLW_B    101531648ull
#define L1IMW_B   (LVLW_B)
#define L1W1_B    (LVLW_B + 212992ull)
#define L1W2_B    (LVLW_B + 229376ull)
#define L1F1_B    (LVLW_B + 245760ull)
#define L1F2_B    (LVLW_B + 262144ull)
#define L2IMW_B   (LVLW_B + 278528ull)
#define L2W1_B    (LVLW_B + 491520ull)
#define L2W2_B    (LVLW_B + 507904ull)
#define L2F1_B    (LVLW_B + 524288ull)
#define L2F2_B    (LVLW_B + 540672ull)
#define SPE2_B    102088704ull
#define SPEIN_B   (SPE2_B)
#define X2_B      (SPE2_B + 331776ull)
#define R2_B      (SPE2_B + 1658880ull)
#define T2_B      (SPE2_B + 2985984ull)
#define LRSPE_B   (SPE2_B + 4313088ull)

extern "C" void kernel_launch(void* const* d_in, const int* in_sizes, int n_in,
                              void* d_out, int out_size, void* d_ws, size_t ws_size,
                              hipStream_t stream) {
    (void)in_sizes; (void)n_in; (void)out_size; (void)ws_size;
    const float* HR_MSI     = (const float*)d_in[0];
    const float* lms        = (const float*)d_in[1];
    const float* LR_HSI     = (const float*)d_in[2];
    const float* spa_head_w = (const float*)d_in[3];
    const float* spa_head_b = (const float*)d_in[4];
    const float* spa_res_w  = (const float*)d_in[5];
    const float* spa_res_b  = (const float*)d_in[6];
    const float* spa_tail_w = (const float*)d_in[7];
    const float* spa_tail_b = (const float*)d_in[8];
    const float* spe_head_w = (const float*)d_in[9];
    const float* spe_head_b = (const float*)d_in[10];
    const float* spe_res_w  = (const float*)d_in[11];
    const float* spe_res_b  = (const float*)d_in[12];
    const float* spe_tail_w = (const float*)d_in[13];
    const float* spe_tail_b = (const float*)d_in[14];
    const float* l1_w   = (const float*)d_in[15];
    const float* l1_b   = (const float*)d_in[16];
    const float* wg32_w1 = (const float*)d_in[17];
    const float* wg32_b1 = (const float*)d_in[18];
    const float* wg32_w2 = (const float*)d_in[19];
    const float* wg32_b2 = (const float*)d_in[20];
    const float* ffn32_w1 = (const float*)d_in[21];
    const float* ffn32_b1 = (const float*)d_in[22];
    const float* ffn32_w2 = (const float*)d_in[23];
    const float* ffn32_b2 = (const float*)d_in[24];
    const float* l2_w   = (const float*)d_in[25];
    const float* l2_b   = (const float*)d_in[26];
    const float* wg64_w1 = (const float*)d_in[27];
    const float* wg64_b1 = (const float*)d_in[28];
    const float* wg64_w2 = (const float*)d_in[29];
    const float* wg64_b2 = (const float*)d_in[30];
    const float* ffn64_w1 = (const float*)d_in[31];
    const float* ffn64_b1 = (const float*)d_in[32];
    const float* ffn64_w2 = (const float*)d_in[33];
    const float* ffn64_b2 = (const float*)d_in[34];

    char* ws = (char*)d_ws;
    f16* Wp      = (f16*)(ws + WPACK_B);
    f16* Cc      = (f16*)(ws + CC_B);
    f16* SPEin   = (f16*)(ws + SPEIN_B);
    f16* X2h     = (f16*)(ws + X2_B);
    f16* R2h     = (f16*)(ws + R2_B);
    f16* T2h     = (f16*)(ws + T2_B);
    f16* lrspe16 = (f16*)(ws + LRSPE_B);
    f16* Rh      = (f16*)(ws + RH_B);
    f16* Xh      = (f16*)(ws + XH_B);
    f16* Th      = (f16*)(ws + TH_B);
    f16* g32T    = (f16*)(ws + G32_B);
    f16* g16T    = (f16*)(ws + G16_B);
    f16* l1T16   = (f16*)(ws + L1T_B);
    f16* hr16    = (f16*)(ws + HR16_B);
    f16* lvlw    = (f16*)(ws + LVLW_B);
    f16* l1imw = (f16*)(ws + L1IMW_B);
    f16* l1w1  = (f16*)(ws + L1W1_B);
    f16* l1w2  = (f16*)(ws + L1W2_B);
    f16* l1f1  = (f16*)(ws + L1F1_B);
    f16* l1f2  = (f16*)(ws + L1F2_B);
    f16* l2imw = (f16*)(ws + L2IMW_B);
    f16* l2w1  = (f16*)(ws + L2W1_B);
    f16* l2w2  = (f16*)(ws + L2W2_B);
    f16* l2f1  = (f16*)(ws + L2F1_B);
    f16* l2f2  = (f16*)(ws + L2F2_B);

    // zero padded fp16 regions (borders + never-written channels must be 0)
    hipMemsetAsync(ws + CC_B, 0, 8921088ull, stream);
    hipMemsetAsync(ws + RH_B, 0, 53526528ull, stream);
    hipMemsetAsync(ws + SPE2_B, 0, 5361664ull, stream);

    // pack all conv weights (one launch) and all level weights (one launch)
    pack_w_all<<<10800, 256, 0, stream>>>(spa_head_w, spa_res_w, spa_tail_w,
                                          spe_head_w, spe_res_w, spe_tail_w, Wp);
    pack_lvl_all<<<1064, 256, 0, stream>>>(l1_w, wg32_w1, wg32_w2, ffn32_w1, ffn32_w2,
                                           l2_w, wg64_w1, wg64_w2, ffn64_w1, ffn64_w2,
                                           lvlw);

    // ---- build padded inputs (disjoint regions) ----
    build_cc<<<8704, 256, 0, stream>>>(HR_MSI, lms, Cc, 16 * 64 * 64 * 34);
    build_spe<<<496, 256, 0, stream>>>(LR_HSI, SPEin, 16 * 16 * 16 * 31);

    // ---- fused spa+spe EDSR: 512-thread blocks, grid 512 spa + 128 spe ----
    conv_dual<66, 6, 2, 2, 18, 4, 2, 1, 8><<<640, 512, 0, stream>>>(
        512,
        Cc, Wp + 0, spa_head_b, nullptr, Xh, Rh,
        SPEin, Wp + 1400832, spe_head_b, nullptr, X2h, R2h, 4);
    for (int i = 0; i < 4; ++i) {
        conv_dual<66, 6, 2, 4, 18, 4, 2, 4, 8><<<640, 512, 0, stream>>>(
            512,
            Rh, Wp + 73728 + (size_t)(2 * i) * 147456, spa_res_b + 2 * i * 128, nullptr, Th, nullptr,
            R2h, Wp + 1437696 + (size_t)(2 * i) * 147456, spe_res_b + 2 * i * 128, nullptr, T2h, nullptr, 1);
        conv_dual<66, 6, 2, 4, 18, 4, 2, 4, 8><<<640, 512, 0, stream>>>(
            512,
            Th, Wp + 73728 + (size_t)(2 * i + 1) * 147456, spa_res_b + (2 * i + 1) * 128, nullptr, Rh, nullptr,
            T2h, Wp + 1437696 + (size_t)(2 * i + 1) * 147456, spe_res_b + (2 * i + 1) * 128, nullptr, R2h, nullptr, 2);
    }
    conv_dual<66, 6, 2, 4, 18, 4, 2, 4, 8><<<640, 512, 0, stream>>>(
        512,
        Rh, Wp + 1253376, spa_tail_b, Xh, nullptr, hr16,
        R2h, Wp + 2617344, spe_tail_b, X2h, nullptr, lrspe16, 3);

    // ---- both max pools in one launch ----
    maxpool_both<<<10240, 256, 0, stream>>>(hr16, g32T, g16T);

    // ---- level 1: 32x32 queries, 16 q/block -> l1T16 f16 ----
    level_kernel<<<1024, 256, 0, stream>>>(
        lrspe16, 16, 16, g32T, 32, 32, g16T, 16, 16,
        32, 32, 64,
        l1imw, l1_b, l1w1, wg32_b1, l1w2, wg32_b2,
        l1f1, ffn32_b1, l1f2, ffn32_b2,
        128, 1, 0, nullptr, l1T16, nullptr);

    // ---- level 2: 64x64 queries, 16 q/block, + lms, fp32 NCHW to d_out ----
    level_kernel<<<4096, 256, 0, stream>>>(
        l1T16, 32, 32, hr16, 64, 64, g32T, 32, 32,
        64, 64, 256,
        l2imw, l2_b, l2w1, wg64_b1, l2w2, wg64_b2,
        l2f1, ffn64_b1, l2f2, ffn64_b2,
        31, 0, 1, lms, nullptr, (float*)d_out);
}